// Round 2
// baseline (660.995 us; speedup 1.0000x reference)
//
#include <hip/hip_runtime.h>
#include <hip/hip_bf16.h>

typedef __attribute__((ext_vector_type(8))) short bf16x8;
typedef __attribute__((ext_vector_type(4))) float f32x4;

#define INV_TAU 1.1111111111111112f

constexpr int Bn = 4, Cc = 8192, HWn = 1024, Dn = 512;
constexpr long long OUT_KL     = 2097152LL;
constexpr long long OUT_LOGITS = 2097153LL;
constexpr long long OUT_LOGQY  = 35651585LL;

// ws layout (bytes)
constexpr size_t WS_EMBT = 0;             // bf16 [512][8192]   = 8 MiB
constexpr size_t WS_OHT  = 8ull  << 20;   // bf16 [4096][8192]  = 64 MiB
constexpr size_t WS_P1   = 72ull << 20;   // float4 [64][4096]  = 4 MiB
constexpr size_t WS_ST   = 76ull << 20;   // float4 [4096]      = 64 KiB
constexpr size_t WS_GP   = 77ull << 20;   // float [4][2097152] = 32 MiB

struct f4u { float x, y, z, w; };  // align(4) → dwordx4 w/ 4B alignment ok

__device__ __forceinline__ unsigned short f2bf(float f) {
  unsigned u = __float_as_uint(f);
  u += 0x7fffu + ((u >> 16) & 1u);
  return (unsigned short)(u >> 16);
}

__device__ __forceinline__ void onl(float& m, float& s, float v) {
  const float M = fmaxf(m, v);
  const float e = __expf(fminf(m, v) - M);   // exp(-|v-m|), exp(-inf)=0 on first
  s = (v > m) ? (s * e + 1.0f) : (s + e);
  m = M;
}

__device__ __forceinline__ void mrg(float& m, float& s, float mb, float sb) {
  const float M = fmaxf(m, mb);
  s = s * __expf(m - M) + sb * __expf(mb - M);
  m = M;
}

__device__ __forceinline__ void gload_lds16(const void* g, void* l) {
  __builtin_amdgcn_global_load_lds((const __attribute__((address_space(1))) void*)g,
                                   (__attribute__((address_space(3))) void*)l, 16, 0, 0);
}

// ---------------- K0: emb [C][D] fp32 -> embT bf16 [D][C] ----------------
__global__ __launch_bounds__(256) void qz_k0(const float* __restrict__ emb,
                                             unsigned short* __restrict__ embT) {
  const int c0 = blockIdx.x * 64, d0 = blockIdx.y * 64;
  __shared__ float es[64][65];
  const int t = threadIdx.x;
  const int rr = t >> 4, q4 = (t & 15) * 4;
#pragma unroll
  for (int p = 0; p < 4; ++p) {
    const int row = p * 16 + rr;  // c within tile
    *(float4*)&es[row][q4] = *(const float4*)(emb + (size_t)(c0 + row) * Dn + d0 + q4);
  }
  __syncthreads();
#pragma unroll
  for (int p = 0; p < 4; ++p) {
    const int di = p * 16 + rr;   // d within tile
    ushort4 o;
    o.x = f2bf(es[q4 + 0][di]); o.y = f2bf(es[q4 + 1][di]);
    o.z = f2bf(es[q4 + 2][di]); o.w = f2bf(es[q4 + 3][di]);
    *(ushort4*)(embT + (size_t)(d0 + di) * Cc + c0 + q4) = o;
  }
}

// ---------------- K1a: per-pixel online softmax stats, partial over C-chunks
__global__ __launch_bounds__(256) void qz_k1a(const float* __restrict__ x,
                                              const float* __restrict__ g,
                                              float4* __restrict__ part1) {
  const int pt = blockIdx.x;          // 16 pixel tiles of 256
  const int cch = blockIdx.y;         // 64 chunks of 128 channels
  const int b = pt >> 2, hw0 = (pt & 3) * 256;
  const int t = threadIdx.x, lane = t & 63, cg = t >> 6;
  const int hw = hw0 + lane * 4;
  const size_t base = (size_t)b * Cc * HWn + hw;
  const int c0 = cch * 128;
  float m1[4], s1[4], m2[4], s2[4];
#pragma unroll
  for (int j = 0; j < 4; ++j) { m1[j] = m2[j] = -INFINITY; s1[j] = s2[j] = 0.f; }
#pragma unroll 4
  for (int c = c0 + cg; c < c0 + 128; c += 4) {
    const float4 xv = *(const float4*)(x + base + (size_t)c * HWn);
    const float4 gv = *(const float4*)(g + base + (size_t)c * HWn);
    const float xa[4] = {xv.x, xv.y, xv.z, xv.w};
    const float ga[4] = {gv.x, gv.y, gv.z, gv.w};
#pragma unroll
    for (int j = 0; j < 4; ++j) {
      onl(m1[j], s1[j], (xa[j] + ga[j]) * INV_TAU);
      onl(m2[j], s2[j], xa[j]);
    }
  }
  __shared__ float4 red[3][64][4];
  if (cg) {
#pragma unroll
    for (int j = 0; j < 4; ++j)
      red[cg - 1][lane][j] = make_float4(m1[j], s1[j], m2[j], s2[j]);
  }
  __syncthreads();
  if (!cg) {
#pragma unroll
    for (int k = 0; k < 3; ++k)
#pragma unroll
      for (int j = 0; j < 4; ++j) {
        const float4 r = red[k][lane][j];
        mrg(m1[j], s1[j], r.x, r.y);
        mrg(m2[j], s2[j], r.z, r.w);
      }
#pragma unroll
    for (int j = 0; j < 4; ++j)
      part1[(size_t)cch * 4096 + b * HWn + hw + j] = make_float4(m1[j], s1[j], m2[j], s2[j]);
  }
}

// ---------------- K1b: merge chunk partials -> {m1, 1/s1, m2+log s2}; init KL
__global__ __launch_bounds__(256) void qz_k1b(const float4* __restrict__ part1,
                                              float4* __restrict__ stats,
                                              float* __restrict__ out) {
  const int p = blockIdx.x * 256 + threadIdx.x;  // 0..4095
  float4 a = part1[p];
  float m1 = a.x, s1 = a.y, m2 = a.z, s2 = a.w;
#pragma unroll 8
  for (int k = 1; k < 64; ++k) {
    const float4 q = part1[(size_t)k * 4096 + p];
    mrg(m1, s1, q.x, q.y);
    mrg(m2, s2, q.z, q.w);
  }
  stats[p] = make_float4(m1, 1.0f / s1, m2 + __logf(s2), 0.f);
  if (p == 0) out[OUT_KL] = 36908.701f;  // 4096 * ln(8192)
}

// ---------------- K2: transpose tiles -> logits, log_qy, one_hot bf16, KL
__global__ __launch_bounds__(256) void qz_k2(const float* __restrict__ x,
                                             const float* __restrict__ g,
                                             const float4* __restrict__ stats,
                                             unsigned short* __restrict__ oht,
                                             float* __restrict__ out) {
  const int c0 = blockIdx.x * 64, hw0 = blockIdx.y * 64, b = blockIdx.z;
  __shared__ float xs[64][65];
  __shared__ float ts[64][65];
  __shared__ float4 st[64];
  __shared__ float kred[4];
  const int t = threadIdx.x;
  const int rr = t >> 4, q4 = (t & 15) * 4;
  if (t < 64) st[t] = stats[b * HWn + hw0 + t];
#pragma unroll
  for (int p = 0; p < 4; ++p) {
    const int row = p * 16 + rr;  // c-row in tile
    const size_t gi = ((size_t)(b * Cc + c0 + row)) * HWn + (hw0 + q4);
    const float4 xv = *(const float4*)(x + gi);
    const float4 gv = *(const float4*)(g + gi);
    *(float4*)&xs[row][q4] = xv;
    float4 tv;
    tv.x = (xv.x + gv.x) * INV_TAU; tv.y = (xv.y + gv.y) * INV_TAU;
    tv.z = (xv.z + gv.z) * INV_TAU; tv.w = (xv.w + gv.w) * INV_TAU;
    *(float4*)&ts[row][q4] = tv;
  }
  __syncthreads();
  float kacc = 0.f;
  float* __restrict__ logits = out + OUT_LOGITS;
  float* __restrict__ logqy  = out + OUT_LOGQY;
#pragma unroll
  for (int p = 0; p < 4; ++p) {
    const int hwi = p * 16 + rr;
    const float4 sv = st[hwi];  // {m1, 1/s1, m2+log s2, _}
    const size_t orow = ((size_t)(b * HWn + hw0 + hwi)) * Cc + (c0 + q4);
    float xv[4], lq[4];
    ushort4 ob;
    unsigned short obv[4];
#pragma unroll
    for (int k = 0; k < 4; ++k) {
      const float xx = xs[q4 + k][hwi];
      xv[k] = xx;
      const float l2 = xx - sv.z;
      lq[k] = l2;
      kacc += __expf(l2) * l2;
      obv[k] = f2bf(__expf(ts[q4 + k][hwi] - sv.x) * sv.y);
    }
    f4u lo; lo.x = xv[0]; lo.y = xv[1]; lo.z = xv[2]; lo.w = xv[3];
    *(f4u*)(logits + orow) = lo;
    f4u lf; lf.x = lq[0]; lf.y = lq[1]; lf.z = lq[2]; lf.w = lq[3];
    *(f4u*)(logqy + orow) = lf;
    ob.x = obv[0]; ob.y = obv[1]; ob.z = obv[2]; ob.w = obv[3];
    *(ushort4*)(oht + orow) = ob;
  }
  // block KL reduction
#pragma unroll
  for (int off = 32; off > 0; off >>= 1) kacc += __shfl_down(kacc, off);
  if ((t & 63) == 0) kred[t >> 6] = kacc;
  __syncthreads();
  if (t == 0) atomicAdd(out + OUT_KL, kred[0] + kred[1] + kred[2] + kred[3]);
}

// ---------------- K3: NT-GEMM sampled_part[ks] = embT(128xK) * oht^T(128xK)
// BM=BN=128, BK=64, KSPLIT=4, 4 waves (2x2 of 64x64), 16x16x32 bf16 MFMA,
// global_load_lds(16B) with XOR-swizzled source + swizzled ds_read (T21/T2).
__global__ __launch_bounds__(256) void qz_k3(const unsigned short* __restrict__ embT,
                                             const unsigned short* __restrict__ oht,
                                             float* __restrict__ part) {
  const int nt = blockIdx.x;            // 8 -> hw0
  const int mt = blockIdx.y;            // 4 -> d0
  const int bz = blockIdx.z;            // 16 -> b, ks
  const int b = bz >> 2, ks = bz & 3;
  const int d0 = mt * 128, hw0 = nt * 128, k0 = ks * 2048;
  __shared__ __align__(16) unsigned short As[2][128 * 64];
  __shared__ __align__(16) unsigned short Bs[2][128 * 64];
  const int t = threadIdx.x, w = t >> 6, l = t & 63;
  const int srow = l >> 3;                       // row within 8-row segment
  const int scol = ((l & 7) ^ (l >> 3)) * 8;     // pre-swizzled source col (ushorts)
  const unsigned short* gA = embT + (size_t)d0 * Cc + k0;
  const unsigned short* gB = oht + ((size_t)(b * HWn + hw0)) * Cc + k0;

  auto stage = [&](int buf, int it) {
    const int kk = it * 64;
#pragma unroll
    for (int j = 0; j < 4; ++j) {
      const int seg = j * 4 + w;                 // 0..15, wave-uniform
      const int row = seg * 8 + srow;
      gload_lds16(gA + (size_t)row * Cc + kk + scol, &As[buf][seg * 512]);
      gload_lds16(gB + (size_t)row * Cc + kk + scol, &Bs[buf][seg * 512]);
    }
  };

  f32x4 acc[4][4] = {};
  const int wr = (w >> 1) * 64, wc = (w & 1) * 64;
  const int fr = l & 15;
  const int kg = (l >> 4) & 3;
  const int sw = (fr & 7) * 8;                   // read-side XOR (ushorts)

  stage(0, 0);
  __syncthreads();
  const int NI = 32;  // 2048 / 64
  for (int i = 0; i < NI; ++i) {
    const int cur = i & 1;
    if (i + 1 < NI) stage(cur ^ 1, i + 1);
#pragma unroll
    for (int kh = 0; kh < 2; ++kh) {
      bf16x8 af[4], bv[4];
#pragma unroll
      for (int mi = 0; mi < 4; ++mi) {
        const int r = wr + mi * 16 + fr;
        af[mi] = *(const bf16x8*)&As[cur][r * 64 + ((kh * 32 + kg * 8) ^ sw)];
      }
#pragma unroll
      for (int ni = 0; ni < 4; ++ni) {
        const int r = wc + ni * 16 + fr;
        bv[ni] = *(const bf16x8*)&Bs[cur][r * 64 + ((kh * 32 + kg * 8) ^ sw)];
      }
#pragma unroll
      for (int mi = 0; mi < 4; ++mi)
#pragma unroll
        for (int ni = 0; ni < 4; ++ni)
          acc[mi][ni] = __builtin_amdgcn_mfma_f32_16x16x32_bf16(af[mi], bv[ni], acc[mi][ni], 0, 0, 0);
    }
    __syncthreads();
  }

  float* __restrict__ pb = part + (size_t)(ks * Bn + b) * Dn * HWn;
#pragma unroll
  for (int mi = 0; mi < 4; ++mi)
#pragma unroll
    for (int ni = 0; ni < 4; ++ni)
#pragma unroll
      for (int r = 0; r < 4; ++r) {
        const int dd = d0 + wr + mi * 16 + kg * 4 + r;   // D-frag row
        const int nn = hw0 + wc + ni * 16 + fr;          // D-frag col
        pb[(size_t)dd * HWn + nn] = acc[mi][ni][r];
      }
}

// ---------------- K4: reduce split-K partials -> sampled
__global__ __launch_bounds__(256) void qz_k4(const float* __restrict__ part,
                                             float* __restrict__ out) {
  const size_t i = ((size_t)blockIdx.x * 256 + threadIdx.x) * 4;
  float4 a = *(const float4*)(part + i);
  const float4 b1 = *(const float4*)(part + 2097152ull + i);
  const float4 b2 = *(const float4*)(part + 2ull * 2097152ull + i);
  const float4 b3 = *(const float4*)(part + 3ull * 2097152ull + i);
  a.x += b1.x + b2.x + b3.x;
  a.y += b1.y + b2.y + b3.y;
  a.z += b1.z + b2.z + b3.z;
  a.w += b1.w + b2.w + b3.w;
  *(float4*)(out + i) = a;
}

extern "C" void kernel_launch(void* const* d_in, const int* in_sizes, int n_in,
                              void* d_out, int out_size, void* d_ws, size_t ws_size,
                              hipStream_t stream) {
  const float* x   = (const float*)d_in[0];
  const float* g   = (const float*)d_in[1];
  const float* emb = (const float*)d_in[2];
  float* out = (float*)d_out;
  char* ws = (char*)d_ws;
  unsigned short* embT = (unsigned short*)(ws + WS_EMBT);
  unsigned short* oht  = (unsigned short*)(ws + WS_OHT);
  float4* part1 = (float4*)(ws + WS_P1);
  float4* stats = (float4*)(ws + WS_ST);
  float* gpart  = (float*)(ws + WS_GP);

  qz_k0 <<<dim3(128, 8),    256, 0, stream>>>(emb, embT);
  qz_k1a<<<dim3(16, 64),    256, 0, stream>>>(x, g, part1);
  qz_k1b<<<dim3(16),        256, 0, stream>>>(part1, stats, out);
  qz_k2 <<<dim3(128, 16, 4),256, 0, stream>>>(x, g, stats, oht, out);
  qz_k3 <<<dim3(8, 4, 16),  256, 0, stream>>>(embT, oht, gpart);
  qz_k4 <<<dim3(2048),      256, 0, stream>>>(gpart, out);
}

// Round 3
// 649.320 us; speedup vs baseline: 1.0180x; 1.0180x over previous
//
#include <hip/hip_runtime.h>
#include <hip/hip_bf16.h>

typedef __attribute__((ext_vector_type(8))) short bf16x8;
typedef __attribute__((ext_vector_type(4))) float f32x4;

#define INV_TAU 1.1111111111111112f

constexpr int Bn = 4, Cc = 8192, HWn = 1024, Dn = 512;
constexpr long long OUT_KL     = 2097152LL;
constexpr long long OUT_LOGITS = 2097153LL;
constexpr long long OUT_LOGQY  = 35651585LL;

// ws layout (bytes)
constexpr size_t WS_EMBT = 0;             // bf16 [512][8192]   = 8 MiB
constexpr size_t WS_OHT  = 8ull  << 20;   // bf16 [4096][8192]  = 64 MiB
constexpr size_t WS_P1   = 72ull << 20;   // float4 [64][4096]  = 4 MiB
constexpr size_t WS_ST   = 76ull << 20;   // float4 [4096]      = 64 KiB

struct f4u { float x, y, z, w; };  // align(4) → dwordx4 w/ 4B alignment ok

__device__ __forceinline__ unsigned short f2bf(float f) {
  unsigned u = __float_as_uint(f);
  u += 0x7fffu + ((u >> 16) & 1u);
  return (unsigned short)(u >> 16);
}

__device__ __forceinline__ void onl(float& m, float& s, float v) {
  const float M = fmaxf(m, v);
  const float e = __expf(fminf(m, v) - M);   // exp(-|v-m|), exp(-inf)=0 on first
  s = (v > m) ? (s * e + 1.0f) : (s + e);
  m = M;
}

__device__ __forceinline__ void mrg(float& m, float& s, float mb, float sb) {
  const float M = fmaxf(m, mb);
  s = s * __expf(m - M) + sb * __expf(mb - M);
  m = M;
}

__device__ __forceinline__ void gload_lds16(const void* g, void* l) {
  __builtin_amdgcn_global_load_lds((const __attribute__((address_space(1))) void*)g,
                                   (__attribute__((address_space(3))) void*)l, 16, 0, 0);
}

// ---------------- K0: emb [C][D] fp32 -> embT bf16 [D][C]; zero sampled ----
__global__ __launch_bounds__(256) void qz_k0(const float* __restrict__ emb,
                                             unsigned short* __restrict__ embT,
                                             float* __restrict__ out) {
  const int c0 = blockIdx.x * 64, d0 = blockIdx.y * 64;
  __shared__ float es[64][65];
  const int t = threadIdx.x;
  const int rr = t >> 4, q4 = (t & 15) * 4;
  // zero the sampled region (k3 accumulates into it with atomics)
  {
    const size_t zi = (((size_t)blockIdx.y * 128 + blockIdx.x) * 256 + t) * 8;
    const float4 z = make_float4(0.f, 0.f, 0.f, 0.f);
    *(float4*)(out + zi) = z;
    *(float4*)(out + zi + 4) = z;
  }
#pragma unroll
  for (int p = 0; p < 4; ++p) {
    const int row = p * 16 + rr;  // c within tile
    *(float4*)&es[row][q4] = *(const float4*)(emb + (size_t)(c0 + row) * Dn + d0 + q4);
  }
  __syncthreads();
#pragma unroll
  for (int p = 0; p < 4; ++p) {
    const int di = p * 16 + rr;   // d within tile
    ushort4 o;
    o.x = f2bf(es[q4 + 0][di]); o.y = f2bf(es[q4 + 1][di]);
    o.z = f2bf(es[q4 + 2][di]); o.w = f2bf(es[q4 + 3][di]);
    *(ushort4*)(embT + (size_t)(d0 + di) * Cc + c0 + q4) = o;
  }
}

// ---------------- K1a: per-pixel online softmax stats, partial over C-chunks
__global__ __launch_bounds__(256) void qz_k1a(const float* __restrict__ x,
                                              const float* __restrict__ g,
                                              float4* __restrict__ part1) {
  const int pt = blockIdx.x;          // 16 pixel tiles of 256
  const int cch = blockIdx.y;         // 64 chunks of 128 channels
  const int b = pt >> 2, hw0 = (pt & 3) * 256;
  const int t = threadIdx.x, lane = t & 63, cg = t >> 6;
  const int hw = hw0 + lane * 4;
  const size_t base = (size_t)b * Cc * HWn + hw;
  const int c0 = cch * 128;
  float m1[4], s1[4], m2[4], s2[4];
#pragma unroll
  for (int j = 0; j < 4; ++j) { m1[j] = m2[j] = -INFINITY; s1[j] = s2[j] = 0.f; }
#pragma unroll 4
  for (int c = c0 + cg; c < c0 + 128; c += 4) {
    const float4 xv = *(const float4*)(x + base + (size_t)c * HWn);
    const float4 gv = *(const float4*)(g + base + (size_t)c * HWn);
    const float xa[4] = {xv.x, xv.y, xv.z, xv.w};
    const float ga[4] = {gv.x, gv.y, gv.z, gv.w};
#pragma unroll
    for (int j = 0; j < 4; ++j) {
      onl(m1[j], s1[j], (xa[j] + ga[j]) * INV_TAU);
      onl(m2[j], s2[j], xa[j]);
    }
  }
  __shared__ float4 red[3][64][4];
  if (cg) {
#pragma unroll
    for (int j = 0; j < 4; ++j)
      red[cg - 1][lane][j] = make_float4(m1[j], s1[j], m2[j], s2[j]);
  }
  __syncthreads();
  if (!cg) {
#pragma unroll
    for (int k = 0; k < 3; ++k)
#pragma unroll
      for (int j = 0; j < 4; ++j) {
        const float4 r = red[k][lane][j];
        mrg(m1[j], s1[j], r.x, r.y);
        mrg(m2[j], s2[j], r.z, r.w);
      }
#pragma unroll
    for (int j = 0; j < 4; ++j)
      part1[(size_t)cch * 4096 + b * HWn + hw + j] = make_float4(m1[j], s1[j], m2[j], s2[j]);
  }
}

// ---------------- K1b: merge chunk partials -> {m1, 1/s1, m2+log s2}; init KL
// 4 threads per pixel, each merges 16 chunks, then shfl_xor merge.
__global__ __launch_bounds__(256) void qz_k1b(const float4* __restrict__ part1,
                                              float4* __restrict__ stats,
                                              float* __restrict__ out) {
  const int gid = blockIdx.x * 256 + threadIdx.x;  // 0..16383
  const int p = gid >> 2, sub = gid & 3;
  float m1 = -INFINITY, s1 = 0.f, m2 = -INFINITY, s2 = 0.f;
#pragma unroll
  for (int k = sub; k < 64; k += 4) {
    const float4 q = part1[(size_t)k * 4096 + p];
    mrg(m1, s1, q.x, q.y);
    mrg(m2, s2, q.z, q.w);
  }
#pragma unroll
  for (int off = 1; off <= 2; off <<= 1) {
    const float mb1 = __shfl_xor(m1, off), sb1 = __shfl_xor(s1, off);
    const float mb2 = __shfl_xor(m2, off), sb2 = __shfl_xor(s2, off);
    mrg(m1, s1, mb1, sb1);
    mrg(m2, s2, mb2, sb2);
  }
  if (sub == 0) stats[p] = make_float4(m1, 1.0f / s1, m2 + __logf(s2), 0.f);
  if (gid == 0) out[OUT_KL] = 36908.701f;  // 4096 * ln(8192)
}

// ---------------- K2: transpose tiles -> logits, log_qy, one_hot bf16, KL
__global__ __launch_bounds__(256) void qz_k2(const float* __restrict__ x,
                                             const float* __restrict__ g,
                                             const float4* __restrict__ stats,
                                             unsigned short* __restrict__ oht,
                                             float* __restrict__ out) {
  const int c0 = blockIdx.x * 64, hw0 = blockIdx.y * 64, b = blockIdx.z;
  __shared__ float xs[64][65];
  __shared__ float ts[64][65];
  __shared__ float4 st[64];
  __shared__ float kred[4];
  const int t = threadIdx.x;
  const int rr = t >> 4, q4 = (t & 15) * 4;
  if (t < 64) st[t] = stats[b * HWn + hw0 + t];
#pragma unroll
  for (int p = 0; p < 4; ++p) {
    const int row = p * 16 + rr;  // c-row in tile
    const size_t gi = ((size_t)(b * Cc + c0 + row)) * HWn + (hw0 + q4);
    const float4 xv = *(const float4*)(x + gi);
    const float4 gv = *(const float4*)(g + gi);
    *(float4*)&xs[row][q4] = xv;
    float4 tv;
    tv.x = (xv.x + gv.x) * INV_TAU; tv.y = (xv.y + gv.y) * INV_TAU;
    tv.z = (xv.z + gv.z) * INV_TAU; tv.w = (xv.w + gv.w) * INV_TAU;
    *(float4*)&ts[row][q4] = tv;
  }
  __syncthreads();
  float kacc = 0.f;
  float* __restrict__ logits = out + OUT_LOGITS;
  float* __restrict__ logqy  = out + OUT_LOGQY;
#pragma unroll
  for (int p = 0; p < 4; ++p) {
    const int hwi = p * 16 + rr;
    const float4 sv = st[hwi];  // {m1, 1/s1, m2+log s2, _}
    const size_t orow = ((size_t)(b * HWn + hw0 + hwi)) * Cc + (c0 + q4);
    float xv[4], lq[4];
    ushort4 ob;
    unsigned short obv[4];
#pragma unroll
    for (int k = 0; k < 4; ++k) {
      const float xx = xs[q4 + k][hwi];
      xv[k] = xx;
      const float l2 = xx - sv.z;
      lq[k] = l2;
      kacc += __expf(l2) * l2;
      obv[k] = f2bf(__expf(ts[q4 + k][hwi] - sv.x) * sv.y);
    }
    f4u lo; lo.x = xv[0]; lo.y = xv[1]; lo.z = xv[2]; lo.w = xv[3];
    *(f4u*)(logits + orow) = lo;
    f4u lf; lf.x = lq[0]; lf.y = lq[1]; lf.z = lq[2]; lf.w = lq[3];
    *(f4u*)(logqy + orow) = lf;
    ob.x = obv[0]; ob.y = obv[1]; ob.z = obv[2]; ob.w = obv[3];
    *(ushort4*)(oht + orow) = ob;
  }
  // block KL reduction
#pragma unroll
  for (int off = 32; off > 0; off >>= 1) kacc += __shfl_down(kacc, off);
  if ((t & 63) == 0) kred[t >> 6] = kacc;
  __syncthreads();
  if (t == 0) atomicAdd(out + OUT_KL, kred[0] + kred[1] + kred[2] + kred[3]);
}

// ---------------- K3: NT-GEMM sampled += embT(128xK) * oht^T(128xK)
// BM=BN=128, BK=64, KSPLIT=4, 8 waves (2x4 of 64x32), 16x16x32 bf16 MFMA,
// global_load_lds(16B) with XOR-swizzled source + swizzled ds_read (T21/T2).
// Split-K partials accumulated via global fp32 atomics (sampled zeroed by k0).
__global__ __launch_bounds__(512) void qz_k3(const unsigned short* __restrict__ embT,
                                             const unsigned short* __restrict__ oht,
                                             float* __restrict__ out) {
  const int nt = blockIdx.x;            // 8 -> hw0
  const int mt = blockIdx.y;            // 4 -> d0
  const int bz = blockIdx.z;            // 16 -> b, ks
  const int b = bz >> 2, ks = bz & 3;
  const int d0 = mt * 128, hw0 = nt * 128, k0 = ks * 2048;
  __shared__ __align__(16) unsigned short As[2][128 * 64];
  __shared__ __align__(16) unsigned short Bs[2][128 * 64];
  const int t = threadIdx.x, w = t >> 6, l = t & 63;
  const int srow = l >> 3;                       // row within 8-row segment
  const int scol = ((l & 7) ^ (l >> 3)) * 8;     // pre-swizzled source col (ushorts)
  const unsigned short* gA = embT + (size_t)d0 * Cc + k0;
  const unsigned short* gB = oht + ((size_t)(b * HWn + hw0)) * Cc + k0;

  auto stage = [&](int buf, int it) {
    const int kk = it * 64;
#pragma unroll
    for (int j = 0; j < 2; ++j) {
      const int seg = j * 8 + w;                 // 0..15, wave-uniform
      const int row = seg * 8 + srow;
      gload_lds16(gA + (size_t)row * Cc + kk + scol, &As[buf][seg * 512]);
      gload_lds16(gB + (size_t)row * Cc + kk + scol, &Bs[buf][seg * 512]);
    }
  };

  f32x4 acc[4][2] = {};
  const int wr = (w >> 2) * 64, wc = (w & 3) * 32;
  const int fr = l & 15;
  const int kg = (l >> 4) & 3;
  const int sw = (fr & 7) * 8;                   // read-side XOR (ushorts)

  stage(0, 0);
  __syncthreads();
  const int NI = 32;  // 2048 / 64
  for (int i = 0; i < NI; ++i) {
    const int cur = i & 1;
    if (i + 1 < NI) stage(cur ^ 1, i + 1);
#pragma unroll
    for (int kh = 0; kh < 2; ++kh) {
      bf16x8 af[4], bv[2];
#pragma unroll
      for (int mi = 0; mi < 4; ++mi) {
        const int r = wr + mi * 16 + fr;
        af[mi] = *(const bf16x8*)&As[cur][r * 64 + ((kh * 32 + kg * 8) ^ sw)];
      }
#pragma unroll
      for (int ni = 0; ni < 2; ++ni) {
        const int r = wc + ni * 16 + fr;
        bv[ni] = *(const bf16x8*)&Bs[cur][r * 64 + ((kh * 32 + kg * 8) ^ sw)];
      }
#pragma unroll
      for (int mi = 0; mi < 4; ++mi)
#pragma unroll
        for (int ni = 0; ni < 2; ++ni)
          acc[mi][ni] = __builtin_amdgcn_mfma_f32_16x16x32_bf16(af[mi], bv[ni], acc[mi][ni], 0, 0, 0);
    }
    __syncthreads();
  }

  float* __restrict__ ob = out + (size_t)b * Dn * HWn;
#pragma unroll
  for (int mi = 0; mi < 4; ++mi)
#pragma unroll
    for (int ni = 0; ni < 2; ++ni)
#pragma unroll
      for (int r = 0; r < 4; ++r) {
        const int dd = d0 + wr + mi * 16 + kg * 4 + r;   // D-frag row
        const int nn = hw0 + wc + ni * 16 + fr;          // D-frag col
        atomicAdd(&ob[(size_t)dd * HWn + nn], acc[mi][ni][r]);
      }
}

extern "C" void kernel_launch(void* const* d_in, const int* in_sizes, int n_in,
                              void* d_out, int out_size, void* d_ws, size_t ws_size,
                              hipStream_t stream) {
  const float* x   = (const float*)d_in[0];
  const float* g   = (const float*)d_in[1];
  const float* emb = (const float*)d_in[2];
  float* out = (float*)d_out;
  char* ws = (char*)d_ws;
  unsigned short* embT = (unsigned short*)(ws + WS_EMBT);
  unsigned short* oht  = (unsigned short*)(ws + WS_OHT);
  float4* part1 = (float4*)(ws + WS_P1);
  float4* stats = (float4*)(ws + WS_ST);

  qz_k0 <<<dim3(128, 8),    256, 0, stream>>>(emb, embT, out);
  qz_k1a<<<dim3(16, 64),    256, 0, stream>>>(x, g, part1);
  qz_k1b<<<dim3(64),        256, 0, stream>>>(part1, stats, out);
  qz_k2 <<<dim3(128, 16, 4),256, 0, stream>>>(x, g, stats, oht, out);
  qz_k3 <<<dim3(8, 4, 16),  512, 0, stream>>>(embT, oht, out);
}